// Round 1
// baseline (4074.866 us; speedup 1.0000x reference)
//
#include <hip/hip_runtime.h>

#define N_NODES 10000
#define N_EDGES 320000
#define HASH_LOG 20
#define HASH_SZ (1 << HASH_LOG)
#define HASH_MASK (HASH_SZ - 1)
#define EMPTY_KEY 0xFFFFFFFFu

typedef unsigned int u32;
typedef unsigned short u16;

__device__ __forceinline__ float bf2f(u16 v) {
    return __uint_as_float(((u32)v) << 16);
}
__device__ __forceinline__ u16 f2b(float f) {
    u32 x = __float_as_uint(f);
    return (u16)((x + 0x7FFFu + ((x >> 16) & 1u)) >> 16);
}
__device__ __forceinline__ void unpack8(uint4 u, float* f) {
    f[0] = __uint_as_float(u.x << 16); f[1] = __uint_as_float(u.x & 0xFFFF0000u);
    f[2] = __uint_as_float(u.y << 16); f[3] = __uint_as_float(u.y & 0xFFFF0000u);
    f[4] = __uint_as_float(u.z << 16); f[5] = __uint_as_float(u.z & 0xFFFF0000u);
    f[6] = __uint_as_float(u.w << 16); f[7] = __uint_as_float(u.w & 0xFFFF0000u);
}

// ---------------- K1: degree counts + hash insert (min edge index per (s,d) key)
__global__ __launch_bounds__(256) void k_hash_build(
    const int* __restrict__ ei, u32* __restrict__ hkey, int* __restrict__ hval,
    int* __restrict__ cs, int* __restrict__ cd)
{
    int e = blockIdx.x * 256 + threadIdx.x;
    int s = ei[e], d = ei[N_EDGES + e];
    atomicAdd(&cs[s], 1);
    atomicAdd(&cd[d], 1);
    u32 key = (u32)(s * N_NODES + d);
    u32 h = (key * 2654435761u) >> (32 - HASH_LOG);
    for (;;) {
        u32 prev = atomicCAS(&hkey[h], EMPTY_KEY, key);
        if (prev == EMPTY_KEY || prev == key) { atomicMin(&hval[h], e); break; }
        h = (h + 1) & HASH_MASK;
    }
}

// ---------------- K2: reverse-edge lookup
__global__ __launch_bounds__(256) void k_rev_lookup(
    const int* __restrict__ ei, const u32* __restrict__ hkey,
    const int* __restrict__ hval, int* __restrict__ rev)
{
    int e = blockIdx.x * 256 + threadIdx.x;
    int s = ei[e], d = ei[N_EDGES + e];
    u32 rkey = (u32)(d * N_NODES + s);
    u32 h = (rkey * 2654435761u) >> (32 - HASH_LOG);
    int r = -1;
    for (;;) {
        u32 k = hkey[h];
        if (k == EMPTY_KEY) break;
        if (k == rkey) { r = hval[h]; break; }
        h = (h + 1) & HASH_MASK;
    }
    rev[e] = r;
}

// ---------------- K4: node-level projections: xq=x@Wq+bq, xv=x@Wv+bv,
//                  Pn = x@We1[0:128] + be1, Qn = x@We1[384:512]  (all bf16 out)
__global__ __launch_bounds__(256) void k_node_proj(
    const float* __restrict__ x,
    const float* __restrict__ Wq, const float* __restrict__ bq,
    const float* __restrict__ Wv, const float* __restrict__ bv,
    const float* __restrict__ We1, const float* __restrict__ be1,
    u16* __restrict__ xq, u16* __restrict__ xv,
    u16* __restrict__ Pn, u16* __restrict__ Qn)
{
    __shared__ float XT[128 * 36];
    __shared__ float Ws[16 * 128];
    const int t = threadIdx.x;
    const int nb = blockIdx.x, y = blockIdx.y;
    const int n0 = nb * 32;
    {
        int nl = t & 31;
        int n = n0 + nl; if (n >= N_NODES) n = N_NODES - 1;
        int k0 = (t >> 5) * 16;
        const float4* xp = (const float4*)(x + (size_t)n * 128 + k0);
#pragma unroll
        for (int i = 0; i < 4; i++) {
            float4 v = xp[i];
            XT[(k0 + 4 * i + 0) * 36 + nl] = v.x;
            XT[(k0 + 4 * i + 1) * 36 + nl] = v.y;
            XT[(k0 + 4 * i + 2) * 36 + nl] = v.z;
            XT[(k0 + 4 * i + 3) * 36 + nl] = v.w;
        }
    }
    const int col = t & 127, rb = t >> 7;
    float acc[16];
#pragma unroll
    for (int j = 0; j < 16; j++) acc[j] = 0.f;
    for (int kc = 0; kc < 8; kc++) {
        __syncthreads();
#pragma unroll
        for (int i = 0; i < 2; i++) {
            int f4 = t + 256 * i;      // 512 float4 = 16x128
            int row = f4 >> 5, c4 = (f4 & 31) * 4;
            int kg = kc * 16 + row;
            const float* srcw;
            if (y == 0)      srcw = Wq + (size_t)kg * 128 + c4;
            else if (y == 1) srcw = Wv + (size_t)kg * 128 + c4;
            else if (y < 5)  srcw = We1 + (size_t)kg * 384 + (y - 2) * 128 + c4;
            else             srcw = We1 + (size_t)(384 + kg) * 384 + (y - 5) * 128 + c4;
            *(float4*)&Ws[row * 128 + c4] = *(const float4*)srcw;
        }
        __syncthreads();
#pragma unroll
        for (int k = 0; k < 16; k++) {
            float w = Ws[k * 128 + col];
            const float4* ap = (const float4*)&XT[(kc * 16 + k) * 36 + rb * 16];
            float4 a0 = ap[0], a1v = ap[1], a2v = ap[2], a3v = ap[3];
            float ar[16] = {a0.x,a0.y,a0.z,a0.w, a1v.x,a1v.y,a1v.z,a1v.w,
                            a2v.x,a2v.y,a2v.z,a2v.w, a3v.x,a3v.y,a3v.z,a3v.w};
#pragma unroll
            for (int j = 0; j < 16; j++) acc[j] = fmaf(ar[j], w, acc[j]);
        }
    }
    float bias = 0.f;
    if (y == 0) bias = bq[col];
    else if (y == 1) bias = bv[col];
    else if (y < 5) bias = be1[(y - 2) * 128 + col];
#pragma unroll
    for (int j = 0; j < 16; j++) {
        int n = n0 + rb * 16 + j;
        if (n >= N_NODES) continue;
        u16 v = f2b(acc[j] + bias);
        if (y == 0)      xq[(size_t)n * 128 + col] = v;
        else if (y == 1) xv[(size_t)n * 128 + col] = v;
        else if (y < 5)  Pn[(size_t)n * 384 + (y - 2) * 128 + col] = v;
        else             Qn[(size_t)n * 384 + (y - 5) * 128 + col] = v;
    }
}

// ---------------- K6: edge gates = sigmoid(relu(ef@Wg1+bg1)@Wg2+bg2)
__global__ __launch_bounds__(256) void k_gates(
    const float* __restrict__ ef,
    const float* __restrict__ Wg1, const float* __restrict__ bg1,
    const float* __restrict__ Wg2, const float* __restrict__ bg2,
    float* __restrict__ gates)
{
    __shared__ float Wg1s[128 * 64];
    __shared__ float EFT[32 * 68];
    const int t = threadIdx.x;
    const int e0 = blockIdx.x * 64;
#pragma unroll
    for (int i = 0; i < 8; i++) {
        int f4 = t + 256 * i;   // 2048 float4 = 8192 floats
        *(float4*)&Wg1s[f4 * 4] = *(const float4*)&Wg1[f4 * 4];
    }
    const int o = t & 63, eb = t >> 6;
    float acc[16];
#pragma unroll
    for (int j = 0; j < 16; j++) acc[j] = 0.f;
    for (int kc = 0; kc < 4; kc++) {
        __syncthreads();
        {
            int e = t & 63, kk = (t >> 6) * 8;
            const float4* p = (const float4*)&ef[(size_t)(e0 + e) * 128 + kc * 32 + kk];
            float4 v0 = p[0], v1 = p[1];
            EFT[(kk + 0) * 68 + e] = v0.x; EFT[(kk + 1) * 68 + e] = v0.y;
            EFT[(kk + 2) * 68 + e] = v0.z; EFT[(kk + 3) * 68 + e] = v0.w;
            EFT[(kk + 4) * 68 + e] = v1.x; EFT[(kk + 5) * 68 + e] = v1.y;
            EFT[(kk + 6) * 68 + e] = v1.z; EFT[(kk + 7) * 68 + e] = v1.w;
        }
        __syncthreads();
#pragma unroll
        for (int k = 0; k < 32; k++) {
            const float4* ap = (const float4*)&EFT[k * 68 + eb * 16];
            float4 a0 = ap[0], a1v = ap[1], a2v = ap[2], a3v = ap[3];
            float w = Wg1s[(kc * 32 + k) * 64 + o];
            float ar[16] = {a0.x,a0.y,a0.z,a0.w, a1v.x,a1v.y,a1v.z,a1v.w,
                            a2v.x,a2v.y,a2v.z,a2v.w, a3v.x,a3v.y,a3v.z,a3v.w};
#pragma unroll
            for (int j = 0; j < 16; j++) acc[j] = fmaf(ar[j], w, acc[j]);
        }
    }
    float b1 = bg1[o], w2 = Wg2[o], b2 = bg2[0];
#pragma unroll
    for (int j = 0; j < 16; j++) {
        float v = fmaxf(acc[j] + b1, 0.f) * w2;
#pragma unroll
        for (int off = 32; off > 0; off >>= 1) v += __shfl_xor(v, off, 64);
        if ((t & 63) == 0)
            gates[e0 + eb * 16 + j] = 1.f / (1.f + __expf(-(v + b2)));
    }
}

// ---------------- K5: edge MLP + LayerNorm + subj/obj atomic accumulation
__global__ __launch_bounds__(256) void k_edge_mlp(
    const float* __restrict__ ef, const int* __restrict__ ei,
    const int* __restrict__ rev, const float* __restrict__ gates,
    const u16* __restrict__ Pn, const u16* __restrict__ Qn,
    const float* __restrict__ We1, const float* __restrict__ We2,
    const float* __restrict__ be2, const float* __restrict__ ge,
    const float* __restrict__ beta_e,
    float* __restrict__ out_gcn, float* __restrict__ subj, float* __restrict__ obj)
{
    __shared__ float W1s[16 * 384];   // 24.0 KB (reused as We2 chunks 48x128)
    __shared__ float EFT[16 * 36];    //  2.3 KB
    __shared__ u16 H1T[384 * 40];     // 30.0 KB
    __shared__ int srcs[32], dsts[32], revs[32];
    __shared__ float gts[32];
    const int t = threadIdx.x;
    const int e0 = blockIdx.x * 32;
    if (t < 32) {
        srcs[t] = ei[e0 + t]; dsts[t] = ei[N_EDGES + e0 + t];
        revs[t] = rev[e0 + t]; gts[t] = gates[e0 + t];
    }
    const int col0 = t & 63, rg = t >> 6;
    float acc[8][6];
#pragma unroll
    for (int r = 0; r < 8; r++)
#pragma unroll
        for (int j = 0; j < 6; j++) acc[r][j] = 0.f;

    // GEMM1': [ef | gate*rev] (32x256) @ We1[128:384] (256x384)
    for (int kc = 0; kc < 16; kc++) {
        __syncthreads();
#pragma unroll
        for (int i = 0; i < 6; i++) {
            int f4 = t + 256 * i;          // 1536 float4 = 16x384
            int row = f4 / 96, c4 = (f4 % 96) * 4;
            *(float4*)&W1s[row * 384 + c4] =
                *(const float4*)&We1[(size_t)(128 + kc * 16 + row) * 384 + c4];
        }
        {
            int e = t & 31, kk = (t >> 5) * 2;
            int kg = kc * 16 + kk;
            float v0, v1;
            if (kg < 128) {
                float2 p = *(const float2*)&ef[(size_t)(e0 + e) * 128 + kg];
                v0 = p.x; v1 = p.y;
            } else {
                int r = revs[e];
                if (r >= 0) {
                    float2 p = *(const float2*)&ef[(size_t)r * 128 + (kg - 128)];
                    float g = gts[e];
                    v0 = p.x * g; v1 = p.y * g;
                } else { v0 = 0.f; v1 = 0.f; }
            }
            EFT[kk * 36 + e] = v0;
            EFT[(kk + 1) * 36 + e] = v1;
        }
        __syncthreads();
#pragma unroll
        for (int k = 0; k < 16; k++) {
            const float4* ap = (const float4*)&EFT[k * 36 + rg * 8];
            float4 A0 = ap[0], A1v = ap[1];
            float wv[6];
#pragma unroll
            for (int j = 0; j < 6; j++) wv[j] = W1s[k * 384 + col0 + 64 * j];
            float ar[8] = {A0.x,A0.y,A0.z,A0.w, A1v.x,A1v.y,A1v.z,A1v.w};
#pragma unroll
            for (int r = 0; r < 8; r++)
#pragma unroll
                for (int j = 0; j < 6; j++) acc[r][j] = fmaf(ar[r], wv[j], acc[r][j]);
        }
    }
    __syncthreads();
    // add gathered node terms (Pn[src] + Qn[dst], biases folded), relu -> H1T (bf16)
#pragma unroll
    for (int r = 0; r < 8; r++) {
        int row = rg * 8 + r;
        const u16* pn = Pn + (size_t)srcs[row] * 384;
        const u16* qn = Qn + (size_t)dsts[row] * 384;
#pragma unroll
        for (int j = 0; j < 6; j++) {
            int c = col0 + 64 * j;
            float v = acc[r][j] + bf2f(pn[c]) + bf2f(qn[c]);
            H1T[c * 40 + row] = f2b(fmaxf(v, 0.f));
        }
    }
    // GEMM2: h1 (32x384) @ We2 (384x128)
    float acc2[8][2];
#pragma unroll
    for (int r = 0; r < 8; r++) { acc2[r][0] = 0.f; acc2[r][1] = 0.f; }
    for (int kc = 0; kc < 8; kc++) {
        __syncthreads();
#pragma unroll
        for (int i = 0; i < 6; i++) {
            int f4 = t + 256 * i;          // 1536 float4 = 48x128
            int row = f4 >> 5, c4 = (f4 & 31) * 4;
            *(float4*)&W1s[row * 128 + c4] =
                *(const float4*)&We2[(size_t)(kc * 48 + row) * 128 + c4];
        }
        __syncthreads();
#pragma unroll
        for (int k = 0; k < 48; k++) {
            int kg = kc * 48 + k;
            uint4 hv = *(const uint4*)&H1T[kg * 40 + rg * 8];
            float a[8]; unpack8(hv, a);
            float w0 = W1s[k * 128 + col0];
            float w1 = W1s[k * 128 + 64 + col0];
#pragma unroll
            for (int r = 0; r < 8; r++) {
                acc2[r][0] = fmaf(a[r], w0, acc2[r][0]);
                acc2[r][1] = fmaf(a[r], w1, acc2[r][1]);
            }
        }
    }
    // epilogue: +be2, LayerNorm, write gcn, accumulate subj/obj
    float bw0 = be2[col0], bw1 = be2[col0 + 64];
    float g0 = ge[col0], g1v = ge[col0 + 64];
    float bb0 = beta_e[col0], bb1 = beta_e[col0 + 64];
#pragma unroll
    for (int r = 0; r < 8; r++) {
        int row = rg * 8 + r;
        int e = e0 + row;
        float v0 = acc2[r][0] + bw0, v1 = acc2[r][1] + bw1;
        float s = v0 + v1, sq = v0 * v0 + v1 * v1;
#pragma unroll
        for (int off = 32; off > 0; off >>= 1) {
            s += __shfl_xor(s, off, 64);
            sq += __shfl_xor(sq, off, 64);
        }
        float m = s * (1.f / 128.f);
        float var = sq * (1.f / 128.f) - m * m;
        float rstd = rsqrtf(var + 1e-5f);
        float o0 = (v0 - m) * rstd * g0 + bb0;
        float o1 = (v1 - m) * rstd * g1v + bb1;
        out_gcn[(size_t)e * 128 + col0] = o0;
        out_gcn[(size_t)e * 128 + 64 + col0] = o1;
        float* sp = subj + (size_t)srcs[row] * 128;
        float* op = obj + (size_t)dsts[row] * 128;
        atomicAdd(sp + col0, o0);
        atomicAdd(sp + 64 + col0, o1);
        atomicAdd(op + col0, o0);
        atomicAdd(op + 64 + col0, o1);
    }
}

// ---------------- K7: multi-head attention + scatter-max into xxbuf
__global__ __launch_bounds__(256) void k_atten(
    const float* __restrict__ ef, const int* __restrict__ ei,
    const u16* __restrict__ xq, const u16* __restrict__ xv,
    const float* __restrict__ Wpe, const float* __restrict__ bpe,
    const float* __restrict__ A1, const float* __restrict__ a1,
    const float* __restrict__ A2, const float* __restrict__ a2,
    int* __restrict__ xxbuf)
{
    __shared__ float smem[15104];            // 60416 B, manually partitioned
    __shared__ int srcs[32], dsts[32];
    float* EFT = smem;                       // [128][36] f32 (phase A/B)
    float* A1T = smem;                       // [64][72]  f32 (phase C/D, over EFT)
    float* Wc  = smem + 4608;                // [16][128] f32 (phase B)
    float* A2T = smem + 4608;                // [64][32]  f32 (phase C/E, over Wc)
    u16* xqs  = (u16*)(smem + 6656);         // [32][132] bf16
    u16* epsb = (u16*)(smem + 8768);         // [32][132] bf16
    float* T2s = smem + 6656;                // [32][130] f32 (over xqs+epsb)
    u16* T1s  = (u16*)(smem + 10880);        // [64][132] bf16
    float* vs = smem + 10880;                // [32][128] f32 (over T1s, phase F)
    const int t = threadIdx.x;
    const int e0 = blockIdx.x * 32;
    if (t < 32) { srcs[t] = ei[e0 + t]; dsts[t] = ei[N_EDGES + e0 + t]; }
    __syncthreads();
    // phase A: stage ef (transposed) and xq[src] rows
    {
        int e = t & 31, k0 = (t >> 5) * 16;
        const float4* p = (const float4*)&ef[(size_t)(e0 + e) * 128 + k0];
#pragma unroll
        for (int i = 0; i < 4; i++) {
            float4 v = p[i];
            EFT[(k0 + 4 * i + 0) * 36 + e] = v.x;
            EFT[(k0 + 4 * i + 1) * 36 + e] = v.y;
            EFT[(k0 + 4 * i + 2) * 36 + e] = v.z;
            EFT[(k0 + 4 * i + 3) * 36 + e] = v.w;
        }
    }
    {
        int e = t >> 3, c0 = (t & 7) * 16;
        const uint2* p = (const uint2*)&xq[(size_t)srcs[e] * 128 + c0];
        uint2* q = (uint2*)&xqs[e * 132 + c0];
#pragma unroll
        for (int i = 0; i < 4; i++) q[i] = p[i];
    }
    const int col = t & 127, rb = t >> 7;
    // phase B: eproj = ef @ Wpe + bpe
    float acc[16];
#pragma unroll
    for (int j = 0; j < 16; j++) acc[j] = 0.f;
    for (int kc = 0; kc < 8; kc++) {
        __syncthreads();
#pragma unroll
        for (int i = 0; i < 2; i++) {
            int f4 = t + 256 * i;
            int row = f4 >> 5, c4 = (f4 & 31) * 4;
            *(float4*)&Wc[row * 128 + c4] =
                *(const float4*)&Wpe[(size_t)(kc * 16 + row) * 128 + c4];
        }
        __syncthreads();
#pragma unroll
        for (int k = 0; k < 16; k++) {
            const float4* ap = (const float4*)&EFT[(kc * 16 + k) * 36 + rb * 16];
            float4 a0 = ap[0], a1v = ap[1], a2v = ap[2], a3v = ap[3];
            float w = Wc[k * 128 + col];
            float ar[16] = {a0.x,a0.y,a0.z,a0.w, a1v.x,a1v.y,a1v.z,a1v.w,
                            a2v.x,a2v.y,a2v.z,a2v.w, a3v.x,a3v.y,a3v.z,a3v.w};
#pragma unroll
            for (int j = 0; j < 16; j++) acc[j] = fmaf(ar[j], w, acc[j]);
        }
    }
    __syncthreads();
    {
        float bp = bpe[col];
#pragma unroll
        for (int j = 0; j < 16; j++) epsb[(rb * 16 + j) * 132 + col] = f2b(acc[j] + bp);
    }
    __syncthreads();
    // phase C: stage A1^T (f32, over EFT) and A2^T (f32, over Wc)
#pragma unroll
    for (int i = 0; i < 16; i++) {
        int flat = t + 256 * i;            // 4096
        int o = flat & 63, c = flat >> 6;
        A1T[c * 72 + o] = A1[o * 64 + c];
    }
#pragma unroll
    for (int i = 0; i < 8; i++) {
        int flat = t + 256 * i;            // 2048
        int c = flat & 63, o = flat >> 6;
        A2T[c * 32 + o] = A2[o * 64 + c];
    }
    __syncthreads();
    // phase D: T1 = relu(A1 @ H + a1), H = [q; eproj] per head
    float acc1[32];
#pragma unroll
    for (int j = 0; j < 32; j++) acc1[j] = 0.f;
    {
        int e = col >> 2, hh = col & 3;
        const u16* h0 = &xqs[e * 132 + hh];
        const u16* h1 = &epsb[e * 132 + hh];
#pragma unroll 4
        for (int k = 0; k < 32; k++) {
            float hval = bf2f(h0[4 * k]);
            const float4* ap = (const float4*)&A1T[k * 72 + rb * 32];
#pragma unroll
            for (int q4 = 0; q4 < 8; q4++) {
                float4 av = ap[q4];
                acc1[q4 * 4 + 0] = fmaf(av.x, hval, acc1[q4 * 4 + 0]);
                acc1[q4 * 4 + 1] = fmaf(av.y, hval, acc1[q4 * 4 + 1]);
                acc1[q4 * 4 + 2] = fmaf(av.z, hval, acc1[q4 * 4 + 2]);
                acc1[q4 * 4 + 3] = fmaf(av.w, hval, acc1[q4 * 4 + 3]);
            }
        }
#pragma unroll 4
        for (int k = 0; k < 32; k++) {
            float hval = bf2f(h1[4 * k]);
            const float4* ap = (const float4*)&A1T[(k + 32) * 72 + rb * 32];
#pragma unroll
            for (int q4 = 0; q4 < 8; q4++) {
                float4 av = ap[q4];
                acc1[q4 * 4 + 0] = fmaf(av.x, hval, acc1[q4 * 4 + 0]);
                acc1[q4 * 4 + 1] = fmaf(av.y, hval, acc1[q4 * 4 + 1]);
                acc1[q4 * 4 + 2] = fmaf(av.z, hval, acc1[q4 * 4 + 2]);
                acc1[q4 * 4 + 3] = fmaf(av.w, hval, acc1[q4 * 4 + 3]);
            }
        }
    }
#pragma unroll
    for (int j = 0; j < 32; j++) {
        int o = rb * 32 + j;
        T1s[o * 132 + col] = f2b(fmaxf(acc1[j] + a1[o], 0.f));
    }
    __syncthreads();
    // phase E: T2 = A2 @ T1 + a2
    float acc2[16];
#pragma unroll
    for (int j = 0; j < 16; j++) acc2[j] = 0.f;
#pragma unroll 4
    for (int k = 0; k < 64; k++) {
        float hval = bf2f(T1s[k * 132 + col]);
        const float4* ap = (const float4*)&A2T[k * 32 + rb * 16];
#pragma unroll
        for (int q4 = 0; q4 < 4; q4++) {
            float4 av = ap[q4];
            acc2[q4 * 4 + 0] = fmaf(av.x, hval, acc2[q4 * 4 + 0]);
            acc2[q4 * 4 + 1] = fmaf(av.y, hval, acc2[q4 * 4 + 1]);
            acc2[q4 * 4 + 2] = fmaf(av.z, hval, acc2[q4 * 4 + 2]);
            acc2[q4 * 4 + 3] = fmaf(av.w, hval, acc2[q4 * 4 + 3]);
        }
    }
    __syncthreads();   // phase D reads of xqs/epsb done; safe to overwrite with T2s
#pragma unroll
    for (int j = 0; j < 16; j++) {
        int o = rb * 16 + j;
        T2s[o * 130 + col] = acc2[j] + a2[o];
    }
    __syncthreads();
    // phase F: softmax over o (t<128) || gather value rows xv[dst] (t>=128)
    if (t < 128) {
        float vb[32]; float m = -1e30f;
#pragma unroll
        for (int o = 0; o < 32; o++) { vb[o] = T2s[o * 130 + t]; m = fmaxf(m, vb[o]); }
        float ssum = 0.f;
#pragma unroll
        for (int o = 0; o < 32; o++) { vb[o] = __expf(vb[o] - m); ssum += vb[o]; }
        float inv = 1.f / ssum;
#pragma unroll
        for (int o = 0; o < 32; o++) T2s[o * 130 + t] = vb[o] * inv;
    } else {
        int i = t - 128;
        int e = i >> 2, c0 = (i & 3) * 32;
        const uint4* p = (const uint4*)&xv[(size_t)dsts[e] * 128 + c0];
#pragma unroll
        for (int q4 = 0; q4 < 4; q4++) {
            uint4 u = p[q4];
            float f[8]; unpack8(u, f);
#pragma unroll
            for (int j = 0; j < 8; j++) vs[e * 128 + c0 + q4 * 8 + j] = f[j];
        }
    }
    __syncthreads();
    // phase G: xx_e = prob * value; scatter-max (relu folded) into xxbuf[src]
    {
        int e = t >> 3, cb = t & 7;
        int sbase = srcs[e] * 128;
#pragma unroll
        for (int j = 0; j < 16; j++) {
            int vcol = cb + 8 * j;
            int o = vcol >> 2, hh = vcol & 3;
            float pv = T2s[o * 130 + e * 4 + hh];
            float val = fmaxf(pv * vs[e * 128 + vcol], 0.f);
            atomicMax(&xxbuf[sbase + vcol], __float_as_int(val));
        }
    }
}

// ---------------- K8: twin gate + prop MLP + final LayerNorm (wave per 4 nodes)
__global__ __launch_bounds__(256) void k_node_final(
    const float* __restrict__ x, const float* __restrict__ subj,
    const float* __restrict__ obj, const int* __restrict__ cs,
    const int* __restrict__ cd, const float* __restrict__ xxbuf,
    const float* __restrict__ Wt, const float* __restrict__ bt,
    const float* __restrict__ Wp1, const float* __restrict__ bp1,
    const float* __restrict__ Wp2, const float* __restrict__ bp2,
    const float* __restrict__ gn, const float* __restrict__ bn,
    float* __restrict__ out)
{
    __shared__ float sc[4][4][256];
    const int t = threadIdx.x;
    const int lane = t & 63, w = t >> 6;
    const int n0 = blockIdx.x * 16 + w * 4;
    // step1: scat = [subj/cnt_s , obj/cnt_d]
#pragma unroll
    for (int nn = 0; nn < 4; nn++) {
        int n = n0 + nn;
        float inv_s = 1.f / fmaxf((float)cs[n], 1.f);
        float inv_d = 1.f / fmaxf((float)cd[n], 1.f);
#pragma unroll
        for (int i = 0; i < 4; i++) {
            int c = lane + 64 * i;
            float v = (c < 128) ? subj[(size_t)n * 128 + c] * inv_s
                                : obj[(size_t)n * 128 + (c - 128)] * inv_d;
            sc[w][nn][c] = v;
        }
    }
    __syncthreads();
    // step2: twin = scat @ Wt
    float a8[4][2];
#pragma unroll
    for (int nn = 0; nn < 4; nn++) { a8[nn][0] = 0.f; a8[nn][1] = 0.f; }
#pragma unroll 4
    for (int k = 0; k < 256; k++) {
        float2 wv = *(const float2*)&Wt[(size_t)k * 128 + 2 * lane];
#pragma unroll
        for (int nn = 0; nn < 4; nn++) {
            float h = sc[w][nn][k];
            a8[nn][0] = fmaf(h, wv.x, a8[nn][0]);
            a8[nn][1] = fmaf(h, wv.y, a8[nn][1]);
        }
    }
    __syncthreads();
    // step3: xx2 = relu(segmax)*sigmoid(twin); build hcat=[x, xx2]
    {
        float bt0 = bt[2 * lane], bt1 = bt[2 * lane + 1];
#pragma unroll
        for (int nn = 0; nn < 4; nn++) {
            int n = n0 + nn;
            float tw0 = a8[nn][0] + bt0, tw1 = a8[nn][1] + bt1;
            float xx0 = xxbuf[(size_t)n * 128 + 2 * lane] * (1.f / (1.f + __expf(-tw0)));
            float xx1 = xxbuf[(size_t)n * 128 + 2 * lane + 1] * (1.f / (1.f + __expf(-tw1)));
            float2 xv2 = *(const float2*)&x[(size_t)n * 128 + 2 * lane];
            sc[w][nn][2 * lane] = xv2.x;
            sc[w][nn][2 * lane + 1] = xv2.y;
            sc[w][nn][128 + 2 * lane] = xx0;
            sc[w][nn][129 + 2 * lane] = xx1;
        }
    }
    __syncthreads();
    // step4: p1 = relu(hcat @ Wp1 + bp1)
    float a16[4][4];
#pragma unroll
    for (int nn = 0; nn < 4; nn++)
#pragma unroll
        for (int j = 0; j < 4; j++) a16[nn][j] = 0.f;
#pragma unroll 4
    for (int k = 0; k < 256; k++) {
        float4 wv = *(const float4*)&Wp1[(size_t)k * 256 + 4 * lane];
#pragma unroll
        for (int nn = 0; nn < 4; nn++) {
            float h = sc[w][nn][k];
            a16[nn][0] = fmaf(h, wv.x, a16[nn][0]);
            a16[nn][1] = fmaf(h, wv.y, a16[nn][1]);
            a16[nn][2] = fmaf(h, wv.z, a16[nn][2]);
            a16[nn][3] = fmaf(h, wv.w, a16[nn][3]);
        }
    }
    __syncthreads();
    {
        float q0 = bp1[4 * lane], q1 = bp1[4 * lane + 1];
        float q2 = bp1[4 * lane + 2], q3 = bp1[4 * lane + 3];
#pragma unroll
        for (int nn = 0; nn < 4; nn++) {
            sc[w][nn][4 * lane + 0] = fmaxf(a16[nn][0] + q0, 0.f);
            sc[w][nn][4 * lane + 1] = fmaxf(a16[nn][1] + q1, 0.f);
            sc[w][nn][4 * lane + 2] = fmaxf(a16[nn][2] + q2, 0.f);
            sc[w][nn][4 * lane + 3] = fmaxf(a16[nn][3] + q3, 0.f);
        }
    }
    __syncthreads();
    // step6: p2 = p1 @ Wp2 + bp2, then LayerNorm
    float a8b[4][2];
#pragma unroll
    for (int nn = 0; nn < 4; nn++) { a8b[nn][0] = 0.f; a8b[nn][1] = 0.f; }
#pragma unroll 4
    for (int k = 0; k < 256; k++) {
        float2 wv = *(const float2*)&Wp2[(size_t)k * 128 + 2 * lane];
#pragma unroll
        for (int nn = 0; nn < 4; nn++) {
            float h = sc[w][nn][k];
            a8b[nn][0] = fmaf(h, wv.x, a8b[nn][0]);
            a8b[nn][1] = fmaf(h, wv.y, a8b[nn][1]);
        }
    }
    float bpa = bp2[2 * lane], bpb = bp2[2 * lane + 1];
    float g0 = gn[2 * lane], g1v = gn[2 * lane + 1];
    float b0 = bn[2 * lane], b1v = bn[2 * lane + 1];
#pragma unroll
    for (int nn = 0; nn < 4; nn++) {
        float v0 = a8b[nn][0] + bpa, v1 = a8b[nn][1] + bpb;
        float s = v0 + v1, sq = v0 * v0 + v1 * v1;
#pragma unroll
        for (int off = 32; off > 0; off >>= 1) {
            s += __shfl_xor(s, off, 64);
            sq += __shfl_xor(sq, off, 64);
        }
        float m = s * (1.f / 128.f);
        float var = sq * (1.f / 128.f) - m * m;
        float rstd = rsqrtf(var + 1e-5f);
        float2 o2;
        o2.x = (v0 - m) * rstd * g0 + b0;
        o2.y = (v1 - m) * rstd * g1v + b1v;
        *(float2*)&out[(size_t)(n0 + nn) * 128 + 2 * lane] = o2;
    }
}

extern "C" void kernel_launch(void* const* d_in, const int* in_sizes, int n_in,
                              void* d_out, int out_size, void* d_ws, size_t ws_size,
                              hipStream_t stream) {
    const float* x     = (const float*)d_in[0];
    const float* ef    = (const float*)d_in[1];
    const int*   ei    = (const int*)d_in[2];
    const float* Wg1   = (const float*)d_in[3];
    const float* bg1   = (const float*)d_in[4];
    const float* Wg2   = (const float*)d_in[5];
    const float* bg2   = (const float*)d_in[6];
    const float* We1   = (const float*)d_in[7];
    const float* be1   = (const float*)d_in[8];
    const float* We2   = (const float*)d_in[9];
    const float* be2   = (const float*)d_in[10];
    const float* ge    = (const float*)d_in[11];
    const float* betae = (const float*)d_in[12];
    const float* Wq    = (const float*)d_in[13];
    const float* bq    = (const float*)d_in[14];
    const float* Wpe   = (const float*)d_in[15];
    const float* bpe   = (const float*)d_in[16];
    const float* Wv    = (const float*)d_in[17];
    const float* bv    = (const float*)d_in[18];
    const float* A1    = (const float*)d_in[19];
    const float* a1    = (const float*)d_in[20];
    const float* A2    = (const float*)d_in[21];
    const float* a2    = (const float*)d_in[22];
    const float* Wt    = (const float*)d_in[23];
    const float* bt    = (const float*)d_in[24];
    const float* Wp1   = (const float*)d_in[25];
    const float* bp1   = (const float*)d_in[26];
    const float* Wp2   = (const float*)d_in[27];
    const float* bp2   = (const float*)d_in[28];
    const float* gn    = (const float*)d_in[29];
    const float* bn    = (const float*)d_in[30];

    char* ws = (char*)d_ws;
    size_t off = 0;
    auto take = [&](size_t b) -> void* {
        void* p = ws + off;
        off = (off + b + 255) & ~(size_t)255;
        return p;
    };
    u32*  hkey  = (u32*)take((size_t)HASH_SZ * 4);
    int*  hval  = (int*)take((size_t)HASH_SZ * 4);
    int*  rev   = (int*)take((size_t)N_EDGES * 4);
    float* gates = (float*)take((size_t)N_EDGES * 4);
    u16*  xq    = (u16*)take((size_t)N_NODES * 128 * 2);
    u16*  xv    = (u16*)take((size_t)N_NODES * 128 * 2);
    u16*  Pn    = (u16*)take((size_t)N_NODES * 384 * 2);
    u16*  Qn    = (u16*)take((size_t)N_NODES * 384 * 2);
    // zero-initialized region (contiguous from here)
    float* xxbuf = (float*)take((size_t)N_NODES * 128 * 4);
    float* subj  = (float*)take((size_t)N_NODES * 128 * 4);
    float* obj   = (float*)take((size_t)N_NODES * 128 * 4);
    int*   cs    = (int*)take((size_t)N_NODES * 4);
    int*   cd    = (int*)take((size_t)N_NODES * 4);
    size_t zbytes = (size_t)((ws + off) - (char*)xxbuf);

    hipMemsetAsync(hkey, 0xFF, (size_t)HASH_SZ * 4, stream);
    hipMemsetAsync(hval, 0x7F, (size_t)HASH_SZ * 4, stream);
    hipMemsetAsync(xxbuf, 0, zbytes, stream);

    float* out_xx  = (float*)d_out;
    float* out_gcn = (float*)d_out + (size_t)N_NODES * 128;

    k_hash_build<<<N_EDGES / 256, 256, 0, stream>>>(ei, hkey, hval, cs, cd);
    k_rev_lookup<<<N_EDGES / 256, 256, 0, stream>>>(ei, hkey, hval, rev);
    k_node_proj<<<dim3((N_NODES + 31) / 32, 8), 256, 0, stream>>>(
        x, Wq, bq, Wv, bv, We1, be1, xq, xv, Pn, Qn);
    k_gates<<<N_EDGES / 64, 256, 0, stream>>>(ef, Wg1, bg1, Wg2, bg2, gates);
    k_edge_mlp<<<N_EDGES / 32, 256, 0, stream>>>(
        ef, ei, rev, gates, Pn, Qn, We1, We2, be2, ge, betae,
        out_gcn, subj, obj);
    k_atten<<<N_EDGES / 32, 256, 0, stream>>>(
        ef, ei, xq, xv, Wpe, bpe, A1, a1, A2, a2, (int*)xxbuf);
    k_node_final<<<N_NODES / 16, 256, 0, stream>>>(
        x, subj, obj, cs, cd, xxbuf, Wt, bt, Wp1, bp1, Wp2, bp2, gn, bn, out_xx);
}

// Round 2
// 2161.072 us; speedup vs baseline: 1.8856x; 1.8856x over previous
//
#include <hip/hip_runtime.h>

#define N_NODES 10000
#define N_EDGES 320000
#define HASH_LOG 20
#define HASH_SZ (1 << HASH_LOG)
#define HASH_MASK (HASH_SZ - 1)
#define EMPTY_KEY 0xFFFFFFFFu

typedef unsigned int u32;
typedef unsigned short u16;
typedef __attribute__((ext_vector_type(8))) short bf16x8;
typedef __attribute__((ext_vector_type(4))) float f32x4;

__device__ __forceinline__ float bf2f(u16 v) {
    return __uint_as_float(((u32)v) << 16);
}
__device__ __forceinline__ u16 f2b(float f) {
    u32 x = __float_as_uint(f);
    return (u16)((x + 0x7FFFu + ((x >> 16) & 1u)) >> 16);
}
__device__ __forceinline__ void unpack8(uint4 u, float* f) {
    f[0] = __uint_as_float(u.x << 16); f[1] = __uint_as_float(u.x & 0xFFFF0000u);
    f[2] = __uint_as_float(u.y << 16); f[3] = __uint_as_float(u.y & 0xFFFF0000u);
    f[4] = __uint_as_float(u.z << 16); f[5] = __uint_as_float(u.z & 0xFFFF0000u);
    f[6] = __uint_as_float(u.w << 16); f[7] = __uint_as_float(u.w & 0xFFFF0000u);
}

// ---------------- K1: degree counts + hash insert (min edge index per (s,d) key)
__global__ __launch_bounds__(256) void k_hash_build(
    const int* __restrict__ ei, u32* __restrict__ hkey, int* __restrict__ hval,
    int* __restrict__ cs, int* __restrict__ cd)
{
    int e = blockIdx.x * 256 + threadIdx.x;
    int s = ei[e], d = ei[N_EDGES + e];
    atomicAdd(&cs[s], 1);
    atomicAdd(&cd[d], 1);
    u32 key = (u32)(s * N_NODES + d);
    u32 h = (key * 2654435761u) >> (32 - HASH_LOG);
    for (;;) {
        u32 prev = atomicCAS(&hkey[h], EMPTY_KEY, key);
        if (prev == EMPTY_KEY || prev == key) { atomicMin(&hval[h], e); break; }
        h = (h + 1) & HASH_MASK;
    }
}

// ---------------- K2: reverse-edge lookup
__global__ __launch_bounds__(256) void k_rev_lookup(
    const int* __restrict__ ei, const u32* __restrict__ hkey,
    const int* __restrict__ hval, int* __restrict__ rev)
{
    int e = blockIdx.x * 256 + threadIdx.x;
    int s = ei[e], d = ei[N_EDGES + e];
    u32 rkey = (u32)(d * N_NODES + s);
    u32 h = (rkey * 2654435761u) >> (32 - HASH_LOG);
    int r = -1;
    for (;;) {
        u32 k = hkey[h];
        if (k == EMPTY_KEY) break;
        if (k == rkey) { r = hval[h]; break; }
        h = (h + 1) & HASH_MASK;
    }
    rev[e] = r;
}

// ---------------- K3: transpose+convert weights to bf16: dst[c][r] = src[(r0+r)*C+c]
__global__ __launch_bounds__(256) void k_wtrans(
    const float* __restrict__ src, u16* __restrict__ dst, int R, int C, int r0)
{
    __shared__ float tile[32][33];
    int cb = blockIdx.x * 32, rb = blockIdx.y * 32;
    int tx = threadIdx.x, ty = threadIdx.y;  // 32 x 8
#pragma unroll
    for (int i = 0; i < 4; i++) {
        int r = rb + ty + 8 * i, c = cb + tx;
        tile[ty + 8 * i][tx] = (r < R && c < C) ? src[(size_t)(r0 + r) * C + c] : 0.f;
    }
    __syncthreads();
#pragma unroll
    for (int i = 0; i < 4; i++) {
        int c = cb + ty + 8 * i, r = rb + tx;
        if (c < C && r < R) dst[(size_t)c * R + r] = f2b(tile[tx][ty + 8 * i]);
    }
}

// ---------------- K4: node-level projections: xq=x@Wq+bq, xv=x@Wv+bv,
//                  Pn = x@We1[0:128] + be1, Qn = x@We1[384:512]  (all bf16 out)
__global__ __launch_bounds__(256) void k_node_proj(
    const float* __restrict__ x,
    const float* __restrict__ Wq, const float* __restrict__ bq,
    const float* __restrict__ Wv, const float* __restrict__ bv,
    const float* __restrict__ We1, const float* __restrict__ be1,
    u16* __restrict__ xq, u16* __restrict__ xv,
    u16* __restrict__ Pn, u16* __restrict__ Qn)
{
    __shared__ float XT[128 * 36];
    __shared__ float Ws[16 * 128];
    const int t = threadIdx.x;
    const int nb = blockIdx.x, y = blockIdx.y;
    const int n0 = nb * 32;
    {
        int nl = t & 31;
        int n = n0 + nl; if (n >= N_NODES) n = N_NODES - 1;
        int k0 = (t >> 5) * 16;
        const float4* xp = (const float4*)(x + (size_t)n * 128 + k0);
#pragma unroll
        for (int i = 0; i < 4; i++) {
            float4 v = xp[i];
            XT[(k0 + 4 * i + 0) * 36 + nl] = v.x;
            XT[(k0 + 4 * i + 1) * 36 + nl] = v.y;
            XT[(k0 + 4 * i + 2) * 36 + nl] = v.z;
            XT[(k0 + 4 * i + 3) * 36 + nl] = v.w;
        }
    }
    const int col = t & 127, rb = t >> 7;
    float acc[16];
#pragma unroll
    for (int j = 0; j < 16; j++) acc[j] = 0.f;
    for (int kc = 0; kc < 8; kc++) {
        __syncthreads();
#pragma unroll
        for (int i = 0; i < 2; i++) {
            int f4 = t + 256 * i;      // 512 float4 = 16x128
            int row = f4 >> 5, c4 = (f4 & 31) * 4;
            int kg = kc * 16 + row;
            const float* srcw;
            if (y == 0)      srcw = Wq + (size_t)kg * 128 + c4;
            else if (y == 1) srcw = Wv + (size_t)kg * 128 + c4;
            else if (y < 5)  srcw = We1 + (size_t)kg * 384 + (y - 2) * 128 + c4;
            else             srcw = We1 + (size_t)(384 + kg) * 384 + (y - 5) * 128 + c4;
            *(float4*)&Ws[row * 128 + c4] = *(const float4*)srcw;
        }
        __syncthreads();
#pragma unroll
        for (int k = 0; k < 16; k++) {
            float w = Ws[k * 128 + col];
            const float4* ap = (const float4*)&XT[(kc * 16 + k) * 36 + rb * 16];
            float4 a0 = ap[0], a1v = ap[1], a2v = ap[2], a3v = ap[3];
            float ar[16] = {a0.x,a0.y,a0.z,a0.w, a1v.x,a1v.y,a1v.z,a1v.w,
                            a2v.x,a2v.y,a2v.z,a2v.w, a3v.x,a3v.y,a3v.z,a3v.w};
#pragma unroll
            for (int j = 0; j < 16; j++) acc[j] = fmaf(ar[j], w, acc[j]);
        }
    }
    float bias = 0.f;
    if (y == 0) bias = bq[col];
    else if (y == 1) bias = bv[col];
    else if (y < 5) bias = be1[(y - 2) * 128 + col];
#pragma unroll
    for (int j = 0; j < 16; j++) {
        int n = n0 + rb * 16 + j;
        if (n >= N_NODES) continue;
        u16 v = f2b(acc[j] + bias);
        if (y == 0)      xq[(size_t)n * 128 + col] = v;
        else if (y == 1) xv[(size_t)n * 128 + col] = v;
        else if (y < 5)  Pn[(size_t)n * 384 + (y - 2) * 128 + col] = v;
        else             Qn[(size_t)n * 384 + (y - 5) * 128 + col] = v;
    }
}

// ---------------- K6: edge gates = sigmoid(relu(ef@Wg1+bg1)@Wg2+bg2)
__global__ __launch_bounds__(256) void k_gates(
    const float* __restrict__ ef,
    const float* __restrict__ Wg1, const float* __restrict__ bg1,
    const float* __restrict__ Wg2, const float* __restrict__ bg2,
    float* __restrict__ gates)
{
    __shared__ float Wg1s[128 * 64];
    __shared__ float EFT[32 * 68];
    const int t = threadIdx.x;
    const int e0 = blockIdx.x * 64;
#pragma unroll
    for (int i = 0; i < 8; i++) {
        int f4 = t + 256 * i;   // 2048 float4 = 8192 floats
        *(float4*)&Wg1s[f4 * 4] = *(const float4*)&Wg1[f4 * 4];
    }
    const int o = t & 63, eb = t >> 6;
    float acc[16];
#pragma unroll
    for (int j = 0; j < 16; j++) acc[j] = 0.f;
    for (int kc = 0; kc < 4; kc++) {
        __syncthreads();
        {
            int e = t & 63, kk = (t >> 6) * 8;
            const float4* p = (const float4*)&ef[(size_t)(e0 + e) * 128 + kc * 32 + kk];
            float4 v0 = p[0], v1 = p[1];
            EFT[(kk + 0) * 68 + e] = v0.x; EFT[(kk + 1) * 68 + e] = v0.y;
            EFT[(kk + 2) * 68 + e] = v0.z; EFT[(kk + 3) * 68 + e] = v0.w;
            EFT[(kk + 4) * 68 + e] = v1.x; EFT[(kk + 5) * 68 + e] = v1.y;
            EFT[(kk + 6) * 68 + e] = v1.z; EFT[(kk + 7) * 68 + e] = v1.w;
        }
        __syncthreads();
#pragma unroll
        for (int k = 0; k < 32; k++) {
            const float4* ap = (const float4*)&EFT[k * 68 + eb * 16];
            float4 a0 = ap[0], a1v = ap[1], a2v = ap[2], a3v = ap[3];
            float w = Wg1s[(kc * 32 + k) * 64 + o];
            float ar[16] = {a0.x,a0.y,a0.z,a0.w, a1v.x,a1v.y,a1v.z,a1v.w,
                            a2v.x,a2v.y,a2v.z,a2v.w, a3v.x,a3v.y,a3v.z,a3v.w};
#pragma unroll
            for (int j = 0; j < 16; j++) acc[j] = fmaf(ar[j], w, acc[j]);
        }
    }
    float b1 = bg1[o], w2 = Wg2[o], b2 = bg2[0];
#pragma unroll
    for (int j = 0; j < 16; j++) {
        float v = fmaxf(acc[j] + b1, 0.f) * w2;
#pragma unroll
        for (int off = 32; off > 0; off >>= 1) v += __shfl_xor(v, off, 64);
        if ((t & 63) == 0)
            gates[e0 + eb * 16 + j] = 1.f / (1.f + __expf(-(v + b2)));
    }
}

// ---------------- K5: edge MLP via MFMA bf16 + LayerNorm + subj/obj atomics
// Block: 256 thr (4 waves), 64 edges. GEMM1: A(64x256)@We1bT -> C1(64x384);
// += Pn[src]+Qn[dst]; relu -> H1 (LDS). GEMM2: H1(64x384)@We2bT -> 64x128; LN.
__global__ __launch_bounds__(256) void k_edge_mlp(
    const float* __restrict__ ef, const int* __restrict__ ei,
    const int* __restrict__ rev, const float* __restrict__ gates,
    const u16* __restrict__ Pn, const u16* __restrict__ Qn,
    const u16* __restrict__ We1bT, const u16* __restrict__ We2bT,
    const float* __restrict__ be2, const float* __restrict__ ge,
    const float* __restrict__ beta_e,
    float* __restrict__ out_gcn, float* __restrict__ subj, float* __restrict__ obj)
{
    __shared__ char ldsbuf[58368];
    __shared__ int srcs[64], dsts[64], revs[64];
    __shared__ float gts[64];
    u16* Abuf = (u16*)ldsbuf;             // [64][264] = 33792 B   (GEMM1)
    u16* B1s  = (u16*)(ldsbuf + 33792);   // [4][384][8] = 24576 B (GEMM1)
    u16* H1   = (u16*)ldsbuf;             // [64][392] = 50176 B   (GEMM2, overlaps)
    u16* B2s  = (u16*)(ldsbuf + 50176);   // [4][128][8] = 8192 B  (GEMM2)

    const int t = threadIdx.x;
    const int e0 = blockIdx.x * 64;
    const int w = t >> 6, lane = t & 63, q8 = lane >> 4, lq = lane & 15;

    if (t < 64) {
        srcs[t] = ei[e0 + t]; dsts[t] = ei[N_EDGES + e0 + t];
        revs[t] = rev[e0 + t]; gts[t] = gates[e0 + t];
    }
    __syncthreads();
    // ---- stage A = [bf16(ef) | bf16(gate*rev)] into Abuf
    {
        int r = t >> 2, part = t & 3;
        int e = e0 + r;
        u16* arow = Abuf + r * 264;
        const float* efr = ef + (size_t)e * 128 + part * 32;
#pragma unroll
        for (int i = 0; i < 8; i++) {
            float4 v = *(const float4*)(efr + i * 4);
            u32 lo = (u32)f2b(v.x) | ((u32)f2b(v.y) << 16);
            u32 hi = (u32)f2b(v.z) | ((u32)f2b(v.w) << 16);
            *(uint2*)&arow[part * 32 + i * 4] = make_uint2(lo, hi);
        }
        int rv = revs[r];
        float g = gts[r];
        if (rv >= 0) {
            const float* rr = ef + (size_t)rv * 128 + part * 32;
#pragma unroll
            for (int i = 0; i < 8; i++) {
                float4 v = *(const float4*)(rr + i * 4);
                u32 lo = (u32)f2b(v.x * g) | ((u32)f2b(v.y * g) << 16);
                u32 hi = (u32)f2b(v.z * g) | ((u32)f2b(v.w * g) << 16);
                *(uint2*)&arow[128 + part * 32 + i * 4] = make_uint2(lo, hi);
            }
        } else {
#pragma unroll
            for (int i = 0; i < 8; i++)
                *(uint2*)&arow[128 + part * 32 + i * 4] = make_uint2(0u, 0u);
        }
    }
    // ---- GEMM1: wave w computes rows 0..63 x cols [w*96, w*96+96)
    f32x4 acc1[4][6];
#pragma unroll
    for (int mt = 0; mt < 4; mt++)
#pragma unroll
        for (int nt = 0; nt < 6; nt++) acc1[mt][nt] = (f32x4){0.f, 0.f, 0.f, 0.f};
    for (int kc = 0; kc < 8; kc++) {
        __syncthreads();
#pragma unroll
        for (int i = 0; i < 6; i++) {
            int idx = t + 256 * i;          // 1536 = 4q x 384n
            int q = idx / 384, n = idx - q * 384;
            uint4 v = *(const uint4*)(We1bT + (size_t)n * 256 + kc * 32 + q * 8);
            *(uint4*)(B1s + ((size_t)q * 384 + n) * 8) = v;
        }
        __syncthreads();
        bf16x8 af[4], bf[6];
#pragma unroll
        for (int mt = 0; mt < 4; mt++)
            af[mt] = *(const bf16x8*)(Abuf + (mt * 16 + lq) * 264 + kc * 32 + q8 * 8);
#pragma unroll
        for (int nt = 0; nt < 6; nt++)
            bf[nt] = *(const bf16x8*)(B1s + ((size_t)q8 * 384 + w * 96 + nt * 16 + lq) * 8);
#pragma unroll
        for (int mt = 0; mt < 4; mt++)
#pragma unroll
            for (int nt = 0; nt < 6; nt++)
                acc1[mt][nt] = __builtin_amdgcn_mfma_f32_16x16x32_bf16(
                    af[mt], bf[nt], acc1[mt][nt], 0, 0, 0);
    }
    __syncthreads();
    // ---- write pre-activation C1 -> H1 (bf16). C/D: row=q8*4+r, col=lq per tile
#pragma unroll
    for (int mt = 0; mt < 4; mt++) {
        int m = mt * 16 + q8 * 4;
#pragma unroll
        for (int nt = 0; nt < 6; nt++) {
            int c = w * 96 + nt * 16 + lq;
#pragma unroll
            for (int r = 0; r < 4; r++)
                H1[(m + r) * 392 + c] = f2b(acc1[mt][nt][r]);
        }
    }
    __syncthreads();
    // ---- coalesced pass: H1 += Pn[src]+Qn[dst]; relu
    {
        int r = t >> 2, cb = (t & 3) * 96;
        const u16* pr = Pn + (size_t)srcs[r] * 384;
        const u16* qr = Qn + (size_t)dsts[r] * 384;
        u16* hr = H1 + r * 392;
#pragma unroll
        for (int i = 0; i < 12; i++) {
            int c = cb + i * 8;
            uint4 hv = *(uint4*)&hr[c];
            uint4 pv = *(const uint4*)&pr[c];
            uint4 qv = *(const uint4*)&qr[c];
            float hf[8], pf[8], qf[8];
            unpack8(hv, hf); unpack8(pv, pf); unpack8(qv, qf);
            u16 o[8];
#pragma unroll
            for (int j = 0; j < 8; j++) o[j] = f2b(fmaxf(hf[j] + pf[j] + qf[j], 0.f));
            uint4 ov;
            ov.x = (u32)o[0] | ((u32)o[1] << 16);
            ov.y = (u32)o[2] | ((u32)o[3] << 16);
            ov.z = (u32)o[4] | ((u32)o[5] << 16);
            ov.w = (u32)o[6] | ((u32)o[7] << 16);
            *(uint4*)&hr[c] = ov;
        }
    }
    __syncthreads();
    // ---- GEMM2: wave w computes rows [w*16, w*16+16) x cols 0..127
    f32x4 acc2[8];
#pragma unroll
    for (int nt = 0; nt < 8; nt++) acc2[nt] = (f32x4){0.f, 0.f, 0.f, 0.f};
    for (int kc = 0; kc < 12; kc++) {
#pragma unroll
        for (int i = 0; i < 2; i++) {
            int idx = t + 256 * i;          // 512 = 4q x 128n
            int q = idx >> 7, n = idx & 127;
            uint4 v = *(const uint4*)(We2bT + (size_t)n * 384 + kc * 32 + q * 8);
            *(uint4*)(B2s + ((size_t)q * 128 + n) * 8) = v;
        }
        __syncthreads();
        bf16x8 a = *(const bf16x8*)(H1 + (w * 16 + lq) * 392 + kc * 32 + q8 * 8);
#pragma unroll
        for (int nt = 0; nt < 8; nt++) {
            bf16x8 b = *(const bf16x8*)(B2s + ((size_t)q8 * 128 + nt * 16 + lq) * 8);
            acc2[nt] = __builtin_amdgcn_mfma_f32_16x16x32_bf16(a, b, acc2[nt], 0, 0, 0);
        }
        __syncthreads();
    }
    // ---- epilogue: +be2, LayerNorm (row in-quad), store + subj/obj atomics
    {
        float be2v[8], gev[8], bev[8];
#pragma unroll
        for (int nt = 0; nt < 8; nt++) {
            int c = nt * 16 + lq;
            be2v[nt] = be2[c]; gev[nt] = ge[c]; bev[nt] = beta_e[c];
        }
#pragma unroll
        for (int r = 0; r < 4; r++) {
            int m = w * 16 + q8 * 4 + r;
            int e = e0 + m;
            float vals[8];
            float s = 0.f, sq = 0.f;
#pragma unroll
            for (int nt = 0; nt < 8; nt++) {
                float v = acc2[nt][r] + be2v[nt];
                vals[nt] = v; s += v; sq += v * v;
            }
#pragma unroll
            for (int off = 8; off > 0; off >>= 1) {
                s += __shfl_xor(s, off, 64);
                sq += __shfl_xor(sq, off, 64);
            }
            float mean = s * (1.f / 128.f);
            float var = sq * (1.f / 128.f) - mean * mean;
            float rstd = rsqrtf(var + 1e-5f);
            int sN = srcs[m], dN = dsts[m];
            float* og = out_gcn + (size_t)e * 128;
            float* sp = subj + (size_t)sN * 128;
            float* op = obj + (size_t)dN * 128;
#pragma unroll
            for (int nt = 0; nt < 8; nt++) {
                int c = nt * 16 + lq;
                float o = (vals[nt] - mean) * rstd * gev[nt] + bev[nt];
                og[c] = o;
                atomicAdd(sp + c, o);
                atomicAdd(op + c, o);
            }
        }
    }
}

// ---------------- K7: multi-head attention + scatter-max into xxbuf
__global__ __launch_bounds__(256) void k_atten(
    const float* __restrict__ ef, const int* __restrict__ ei,
    const u16* __restrict__ xq, const u16* __restrict__ xv,
    const float* __restrict__ Wpe, const float* __restrict__ bpe,
    const float* __restrict__ A1, const float* __restrict__ a1,
    const float* __restrict__ A2, const float* __restrict__ a2,
    int* __restrict__ xxbuf)
{
    __shared__ float smem[15104];            // 60416 B, manually partitioned
    __shared__ int srcs[32], dsts[32];
    float* EFT = smem;                       // [128][36] f32 (phase A/B)
    float* A1T = smem;                       // [64][72]  f32 (phase C/D, over EFT)
    float* Wc  = smem + 4608;                // [16][128] f32 (phase B)
    float* A2T = smem + 4608;                // [64][32]  f32 (phase C/E, over Wc)
    u16* xqs  = (u16*)(smem + 6656);         // [32][132] bf16
    u16* epsb = (u16*)(smem + 8768);         // [32][132] bf16
    float* T2s = smem + 6656;                // [32][130] f32 (over xqs+epsb)
    u16* T1s  = (u16*)(smem + 10880);        // [64][132] bf16
    float* vs = smem + 10880;                // [32][128] f32 (over T1s, phase F)
    const int t = threadIdx.x;
    const int e0 = blockIdx.x * 32;
    if (t < 32) { srcs[t] = ei[e0 + t]; dsts[t] = ei[N_EDGES + e0 + t]; }
    __syncthreads();
    // phase A: stage ef (transposed) and xq[src] rows
    {
        int e = t & 31, k0 = (t >> 5) * 16;
        const float4* p = (const float4*)&ef[(size_t)(e0 + e) * 128 + k0];
#pragma unroll
        for (int i = 0; i < 4; i++) {
            float4 v = p[i];
            EFT[(k0 + 4 * i + 0) * 36 + e] = v.x;
            EFT[(k0 + 4 * i + 1) * 36 + e] = v.y;
            EFT[(k0 + 4 * i + 2) * 36 + e] = v.z;
            EFT[(k0 + 4 * i + 3) * 36 + e] = v.w;
        }
    }
    {
        int e = t >> 3, c0 = (t & 7) * 16;
        const uint2* p = (const uint2*)&xq[(size_t)srcs[e] * 128 + c0];
        uint2* q = (uint2*)&xqs[e * 132 + c0];
#pragma unroll
        for (int i = 0; i < 4; i++) q[i] = p[i];
    }
    const int col = t & 127, rb = t >> 7;
    // phase B: eproj = ef @ Wpe + bpe
    float acc[16];
#pragma unroll
    for (int j = 0; j < 16; j++) acc[j] = 0.f;
    for (int kc = 0; kc < 8; kc++) {
        __syncthreads();
#pragma unroll
        for (int i = 0; i < 2; i++) {
            int f4 = t + 256 * i;
            int row = f4 >> 5, c4 = (f4 & 31) * 4;
            *(float4*)&Wc[row * 128 + c4] =
                *(const float4*)&Wpe[(size_t)(kc * 16 + row) * 128 + c4];
        }
        __syncthreads();
#pragma unroll
        for (int k = 0; k < 16; k++) {
            const float4* ap = (const float4*)&EFT[(kc * 16 + k) * 36 + rb * 16];
            float4 a0 = ap[0], a1v = ap[1], a2v = ap[2], a3v = ap[3];
            float w = Wc[k * 128 + col];
            float ar[16] = {a0.x,a0.y,a0.z,a0.w, a1v.x,a1v.y,a1v.z,a1v.w,
                            a2v.x,a2v.y,a2v.z,a2v.w, a3v.x,a3v.y,a3v.z,a3v.w};
#pragma unroll
            for (int j = 0; j < 16; j++) acc[j] = fmaf(ar[j], w, acc[j]);
        }
    }
    __syncthreads();
    {
        float bp = bpe[col];
#pragma unroll
        for (int j = 0; j < 16; j++) epsb[(rb * 16 + j) * 132 + col] = f2b(acc[j] + bp);
    }
    __syncthreads();
    // phase C: stage A1^T (f32, over EFT) and A2^T (f32, over Wc)
#pragma unroll
    for (int i = 0; i < 16; i++) {
        int flat = t + 256 * i;            // 4096
        int o = flat & 63, c = flat >> 6;
        A1T[c * 72 + o] = A1[o * 64 + c];
    }
#pragma unroll
    for (int i = 0; i < 8; i++) {
        int flat = t + 256 * i;            // 2048
        int c = flat & 63, o = flat >> 6;
        A2T[c * 32 + o] = A2[o * 64 + c];
    }
    __syncthreads();
    // phase D: T1 = relu(A1 @ H + a1), H = [q; eproj] per head
    float acc1[32];
#pragma unroll
    for (int j = 0; j < 32; j++) acc1[j] = 0.f;
    {
        int e = col >> 2, hh = col & 3;
        const u16* h0 = &xqs[e * 132 + hh];
        const u16* h1 = &epsb[e * 132 + hh];
#pragma unroll 4
        for (int k = 0; k < 32; k++) {
            float hval = bf2f(h0[4 * k]);
            const float4* ap = (const float4*)&A1T[k * 72 + rb * 32];
#pragma unroll
            for (int q4 = 0; q4 < 8; q4++) {
                float4 av = ap[q4];
                acc1[q4 * 4 + 0] = fmaf(av.x, hval, acc1[q4 * 4 + 0]);
                acc1[q4 * 4 + 1] = fmaf(av.y, hval, acc1[q4 * 4 + 1]);
                acc1[q4 * 4 + 2] = fmaf(av.z, hval, acc1[q4 * 4 + 2]);
                acc1[q4 * 4 + 3] = fmaf(av.w, hval, acc1[q4 * 4 + 3]);
            }
        }
#pragma unroll 4
        for (int k = 0; k < 32; k++) {
            float hval = bf2f(h1[4 * k]);
            const float4* ap = (const float4*)&A1T[(k + 32) * 72 + rb * 32];
#pragma unroll
            for (int q4 = 0; q4 < 8; q4++) {
                float4 av = ap[q4];
                acc1[q4 * 4 + 0] = fmaf(av.x, hval, acc1[q4 * 4 + 0]);
                acc1[q4 * 4 + 1] = fmaf(av.y, hval, acc1[q4 * 4 + 1]);
                acc1[q4 * 4 + 2] = fmaf(av.z, hval, acc1[q4 * 4 + 2]);
                acc1[q4 * 4 + 3] = fmaf(av.w, hval, acc1[q4 * 4 + 3]);
            }
        }
    }
#pragma unroll
    for (int j = 0; j < 32; j++) {
        int o = rb * 32 + j;
        T1s[o * 132 + col] = f2b(fmaxf(acc1[j] + a1[o], 0.f));
    }
    __syncthreads();
    // phase E: T2 = A2 @ T1 + a2
    float acc2[16];
#pragma unroll
    for (int j = 0; j < 16; j++) acc2[j] = 0.f;
#pragma unroll 4
    for (int k = 0; k < 64; k++) {
        float hval = bf2f(T1s[k * 132 + col]);
        const float4* ap = (const float4*)&A2T[k * 32 + rb * 16];
#pragma unroll
        for (int q4 = 0; q4 < 4; q4++) {
            float4 av = ap[q4];
            acc2[q4 * 4 + 0] = fmaf(av.x, hval, acc2[q4 * 4 + 0]);
            acc2[q4 * 4 + 1] = fmaf(av.y, hval, acc2[q4 * 4 + 1]);
            acc2[q4 * 4 + 2] = fmaf(av.z, hval, acc2[q4 * 4 + 2]);
            acc2[q4 * 4 + 3] = fmaf(av.w, hval, acc2[q4 * 4 + 3]);
        }
    }
    __syncthreads();   // phase D reads of xqs/epsb done; safe to overwrite with T2s
#pragma unroll
    for (int j = 0; j < 16; j++) {
        int o = rb * 16 + j;
        T2s[o * 130 + col] = acc2[j] + a2[o];
    }
    __syncthreads();
    // phase F: softmax over o (t<128) || gather value rows xv[dst] (t>=128)
    if (t < 128) {
        float vb[32]; float m = -1e30f;
#pragma unroll
        for (int o = 0; o < 32; o++) { vb[o] = T2s[o * 130 + t]; m = fmaxf(m, vb[o]); }
        float ssum = 0.f;
#pragma unroll
        for (int o = 0; o < 32; o++) { vb[o] = __expf(vb[o] - m); ssum += vb[o]; }
        float inv = 1.f / ssum;
#pragma unroll
        for (int o = 0; o < 32; o++) T2s[o * 130 + t] = vb[o] * inv;
    } else {
        int i = t - 128;
        int e = i >> 2, c0 = (i & 3) * 32;
        const uint4* p = (const uint4*)&xv[(size_t)dsts[e] * 128 + c0];
#pragma unroll
        for (int q4 = 0; q4 < 4; q4++) {
            uint4 u = p[q4];
            float f[8]; unpack8(u, f);
#pragma unroll
            for (int j = 0; j < 8; j++) vs[e * 128 + c0 + q4 * 8 + j] = f[j];
        }
    }
    __syncthreads();
    // phase G: xx_e = prob * value; scatter-max (relu folded) into xxbuf[src]
    {
        int e = t >> 3, cb = t & 7;
        int sbase = srcs[e] * 128;
#pragma unroll
        for (int j = 0; j < 16; j++) {
            int vcol = cb + 8 * j;
            int o = vcol >> 2, hh = vcol & 3;
            float pv = T2s[o * 130 + e * 4 + hh];
            float val = fmaxf(pv * vs[e * 128 + vcol], 0.f);
            atomicMax(&xxbuf[sbase + vcol], __float_as_int(val));
        }
    }
}

// ---------------- K8: twin gate + prop MLP + final LayerNorm (wave per 4 nodes)
__global__ __launch_bounds__(256) void k_node_final(
    const float* __restrict__ x, const float* __restrict__ subj,
    const float* __restrict__ obj, const int* __restrict__ cs,
    const int* __restrict__ cd, const float* __restrict__ xxbuf,
    const float* __restrict__ Wt, const float* __restrict__ bt,
    const float* __restrict__ Wp1, const float* __restrict__ bp1,
    const float* __restrict__ Wp2, const float* __restrict__ bp2,
    const float* __restrict__ gn, const float* __restrict__ bn,
    float* __restrict__ out)
{
    __shared__ float sc[4][4][256];
    const int t = threadIdx.x;
    const int lane = t & 63, w = t >> 6;
    const int n0 = blockIdx.x * 16 + w * 4;
    // step1: scat = [subj/cnt_s , obj/cnt_d]
#pragma unroll
    for (int nn = 0; nn < 4; nn++) {
        int n = n0 + nn;
        float inv_s = 1.f / fmaxf((float)cs[n], 1.f);
        float inv_d = 1.f / fmaxf((float)cd[n], 1.f);
#pragma unroll
        for (int i = 0; i < 4; i++) {
            int c = lane + 64 * i;
            float v = (c < 128) ? subj[(size_t)n * 128 + c] * inv_s
                                : obj[(size_t)n * 128 + (c - 128)] * inv_d;
            sc[w][nn][c] = v;
        }
    }
    __syncthreads();
    // step2: twin = scat @ Wt
    float a8[4][2];
#pragma unroll
    for (int nn = 0; nn < 4; nn++) { a8[nn][0] = 0.f; a8[nn][1] = 0.f; }
#pragma unroll 4
    for (int k = 0; k < 256; k++) {
        float2 wv = *(const float2*)&Wt[(size_t)k * 128 + 2 * lane];
#pragma unroll
        for (int nn = 0; nn < 4; nn++) {
            float h = sc[w][nn][k];
            a8[nn][0] = fmaf(h, wv.x, a8[nn][0]);
            a8[nn][1] = fmaf(h, wv.y, a8[nn][1]);
        }
    }
    __syncthreads();
    // step3: xx2 = relu(segmax)*sigmoid(twin); build hcat=[x, xx2]
    {
        float bt0 = bt[2 * lane], bt1 = bt[2 * lane + 1];
#pragma unroll
        for (int nn = 0; nn < 4; nn++) {
            int n = n0 + nn;
            float tw0 = a8[nn][0] + bt0, tw1 = a8[nn][1] + bt1;
            float xx0 = xxbuf[(size_t)n * 128 + 2 * lane] * (1.f / (1.f + __expf(-tw0)));
            float xx1 = xxbuf[(size_t)n * 128 + 2 * lane + 1] * (1.f / (1.f + __expf(-tw1)));
            float2 xv2 = *(const float2*)&x[(size_t)n * 128 + 2 * lane];
            sc[w][nn][2 * lane] = xv2.x;
            sc[w][nn][2 * lane + 1] = xv2.y;
            sc[w][nn][128 + 2 * lane] = xx0;
            sc[w][nn][129 + 2 * lane] = xx1;
        }
    }
    __syncthreads();
    // step4: p1 = relu(hcat @ Wp1 + bp1)
    float a16[4][4];
#pragma unroll
    for (int nn = 0; nn < 4; nn++)
#pragma unroll
        for (int j = 0; j < 4; j++) a16[nn][j] = 0.f;
#pragma unroll 4
    for (int k = 0; k < 256; k++) {
        float4 wv = *(const float4*)&Wp1[(size_t)k * 256 + 4 * lane];
#pragma unroll
        for (int nn = 0; nn < 4; nn++) {
            float h = sc[w][nn][k];
            a16[nn][0] = fmaf(h, wv.x, a16[nn][0]);
            a16[nn][1] = fmaf(h, wv.y, a16[nn][1]);
            a16[nn][2] = fmaf(h, wv.z, a16[nn][2]);
            a16[nn][3] = fmaf(h, wv.w, a16[nn][3]);
        }
    }
    __syncthreads();
    {
        float q0 = bp1[4 * lane], q1 = bp1[4 * lane + 1];
        float q2 = bp1[4 * lane + 2], q3 = bp1[4 * lane + 3];
#pragma unroll
        for (int nn = 0; nn < 4; nn++) {
            sc[w][nn][4 * lane + 0] = fmaxf(a16[nn][0] + q0, 0.f);
            sc[w][nn][4 * lane + 1] = fmaxf(a16[nn][1] + q1, 0.f);
            sc[w][nn][4 * lane + 2] = fmaxf(a16[nn][2] + q2, 0.f);
            sc[w][nn][4 * lane + 3] = fmaxf(a16[nn][3] + q3, 0.f);
        }
    }
    __syncthreads();
    // step6: p2 = p1 @ Wp2 + bp2, then LayerNorm
    float a8b[4][2];
#pragma unroll
    for (int nn = 0; nn < 4; nn++) { a8b[nn][0] = 0.f; a8b[nn][1] = 0.f; }
#pragma unroll 4
    for (int k = 0; k < 256; k++) {
        float2 wv = *(const float2*)&Wp2[(size_t)k * 128 + 2 * lane];
#pragma unroll
        for (int nn = 0; nn < 4; nn++) {
            float h = sc[w][nn][k];
            a8b[nn][0] = fmaf(h, wv.x, a8b[nn][0]);
            a8b[nn][1] = fmaf(h, wv.y, a8b[nn][1]);
        }
    }
    float bpa = bp2[2 * lane], bpb = bp2[2 * lane + 1];
    float g0 = gn[2 * lane], g1v = gn[2 * lane + 1];
    float b0 = bn[2 * lane], b1v = bn[2 * lane + 1];
#pragma unroll
    for (int nn = 0; nn < 4; nn++) {
        float v0 = a8b[nn][0] + bpa, v1 = a8b[nn][1] + bpb;
        float s = v0 + v1, sq = v0 * v0 + v1 * v1;
#pragma unroll
        for (int off = 32; off > 0; off >>= 1) {
            s += __shfl_xor(s, off, 64);
            sq += __shfl_xor(sq, off, 64);
        }
        float m = s * (1.f / 128.f);
        float var = sq * (1.f / 128.f) - m * m;
        float rstd = rsqrtf(var + 1e-5f);
        float2 o2;
        o2.x = (v0 - m) * rstd * g0 + b0;
        o2.y = (v1 - m) * rstd * g1v + b1v;
        *(float2*)&out[(size_t)(n0 + nn) * 128 + 2 * lane] = o2;
    }
}

extern "C" void kernel_launch(void* const* d_in, const int* in_sizes, int n_in,
                              void* d_out, int out_size, void* d_ws, size_t ws_size,
                              hipStream_t stream) {
    const float* x     = (const float*)d_in[0];
    const float* ef    = (const float*)d_in[1];
    const int*   ei    = (const int*)d_in[2];
    const float* Wg1   = (const float*)d_in[3];
    const float* bg1   = (const float*)d_in[4];
    const float* Wg2   = (const float*)d_in[5];
    const float* bg2   = (const float*)d_in[6];
    const float* We1   = (const float*)d_in[7];
    const float* be1   = (const float*)d_in[8];
    const float* We2   = (const float*)d_in[9];
    const float* be2   = (const float*)d_in[10];
    const float* ge    = (const float*)d_in[11];
    const float* betae = (const float*)d_in[12];
    const float* Wq    = (const float*)d_in[13];
    const float* bq    = (const float*)d_in[14];
    const float* Wpe   = (const float*)d_in[15];
    const float* bpe   = (const float*)d_in[16];
    const float* Wv    = (const float*)d_in[17];
    const float* bv    = (const float*)d_in[18];
    const float* A1    = (const float*)d_in[19];
    const float* a1    = (const float*)d_in[20];
    const float* A2    = (const float*)d_in[21];
    const float* a2    = (const float*)d_in[22];
    const float* Wt    = (const float*)d_in[23];
    const float* bt    = (const float*)d_in[24];
    const float* Wp1   = (const float*)d_in[25];
    const float* bp1   = (const float*)d_in[26];
    const float* Wp2   = (const float*)d_in[27];
    const float* bp2   = (const float*)d_in[28];
    const float* gn    = (const float*)d_in[29];
    const float* bn    = (const float*)d_in[30];

    char* ws = (char*)d_ws;
    size_t off = 0;
    auto take = [&](size_t b) -> void* {
        void* p = ws + off;
        off = (off + b + 255) & ~(size_t)255;
        return p;
    };
    u32*  hkey  = (u32*)take((size_t)HASH_SZ * 4);
    int*  hval  = (int*)take((size_t)HASH_SZ * 4);
    int*  rev   = (int*)take((size_t)N_EDGES * 4);
    float* gates = (float*)take((size_t)N_EDGES * 4);
    u16*  xq    = (u16*)take((size_t)N_NODES * 128 * 2);
    u16*  xv    = (u16*)take((size_t)N_NODES * 128 * 2);
    u16*  Pn    = (u16*)take((size_t)N_NODES * 384 * 2);
    u16*  Qn    = (u16*)take((size_t)N_NODES * 384 * 2);
    u16*  We1bT = (u16*)take((size_t)384 * 256 * 2);
    u16*  We2bT = (u16*)take((size_t)128 * 384 * 2);
    // zero-initialized region (contiguous from here)
    float* xxbuf = (float*)take((size_t)N_NODES * 128 * 4);
    float* subj  = (float*)take((size_t)N_NODES * 128 * 4);
    float* obj   = (float*)take((size_t)N_NODES * 128 * 4);
    int*   cs    = (int*)take((size_t)N_NODES * 4);
    int*   cd    = (int*)take((size_t)N_NODES * 4);
    size_t zbytes = (size_t)((ws + off) - (char*)xxbuf);

    hipMemsetAsync(hkey, 0xFF, (size_t)HASH_SZ * 4, stream);
    hipMemsetAsync(hval, 0x7F, (size_t)HASH_SZ * 4, stream);
    hipMemsetAsync(xxbuf, 0, zbytes, stream);

    float* out_xx  = (float*)d_out;
    float* out_gcn = (float*)d_out + (size_t)N_NODES * 128;

    k_hash_build<<<N_EDGES / 256, 256, 0, stream>>>(ei, hkey, hval, cs, cd);
    k_rev_lookup<<<N_EDGES / 256, 256, 0, stream>>>(ei, hkey, hval, rev);
    k_wtrans<<<dim3(12, 8), dim3(32, 8), 0, stream>>>(We1, We1bT, 256, 384, 128);
    k_wtrans<<<dim3(4, 12), dim3(32, 8), 0, stream>>>(We2, We2bT, 384, 128, 0);
    k_node_proj<<<dim3((N_NODES + 31) / 32, 8), 256, 0, stream>>>(
        x, Wq, bq, Wv, bv, We1, be1, xq, xv, Pn, Qn);
    k_gates<<<N_EDGES / 64, 256, 0, stream>>>(ef, Wg1, bg1, Wg2, bg2, gates);
    k_edge_mlp<<<N_EDGES / 64, 256, 0, stream>>>(
        ef, ei, rev, gates, Pn, Qn, We1bT, We2bT, be2, ge, betae,
        out_gcn, subj, obj);
    k_atten<<<N_EDGES / 32, 256, 0, stream>>>(
        ef, ei, xq, xv, Wpe, bpe, A1, a1, A2, a2, (int*)xxbuf);
    k_node_final<<<N_NODES / 16, 256, 0, stream>>>(
        x, subj, obj, cs, cd, xxbuf, Wt, bt, Wp1, bp1, Wp2, bp2, gn, bn, out_xx);
}